// Round 2
// baseline (660.446 us; speedup 1.0000x reference)
//
#include <hip/hip_runtime.h>

#define DIMS 384
#define SLOPE 0.01f

typedef __attribute__((ext_vector_type(8))) short s16x8;
typedef __attribute__((ext_vector_type(8))) unsigned short u16x8;
typedef __attribute__((ext_vector_type(4))) float f32x4;

typedef __attribute__((address_space(1))) const void gld_src_t;
typedef __attribute__((address_space(3))) void lds_dst_t;
#define GLL16(g, l) __builtin_amdgcn_global_load_lds((gld_src_t*)(g), (lds_dst_t*)(l), 16, 0, 0)

__device__ __forceinline__ unsigned short f2bf(float f) {
  unsigned u = __float_as_uint(f);
  unsigned r = (u + 0x7FFFu + ((u >> 16) & 1u)) >> 16;
  return (unsigned short)r;
}

__device__ __forceinline__ float leaky(float f) { return f >= 0.f ? f : SLOPE * f; }

// ---------------- graph preprocessing ----------------

__global__ void count_kernel(const int* __restrict__ dst, int* __restrict__ cnt, int E) {
  int e = blockIdx.x * blockDim.x + threadIdx.x;
  if (e < E) atomicAdd(&cnt[dst[e]], 1);
}

__global__ void dinv_kernel(const int* __restrict__ cnt, float* __restrict__ dinv, int n) {
  int i = blockIdx.x * blockDim.x + threadIdx.x;
  if (i < n) dinv[i] = 1.0f / sqrtf((float)(cnt[i] + 1));  // +1 self loop
}

__global__ void scan1_kernel(const int* __restrict__ cnt, int* __restrict__ off,
                             int* __restrict__ bsum, int n) {
  __shared__ int s[256];
  int tid = threadIdx.x, gid = blockIdx.x * 256 + tid;
  int v = gid < n ? cnt[gid] : 0;
  s[tid] = v;
  __syncthreads();
  for (int o = 1; o < 256; o <<= 1) {
    int t = tid >= o ? s[tid - o] : 0;
    __syncthreads();
    s[tid] += t;
    __syncthreads();
  }
  if (gid < n) off[gid] = s[tid] - v;  // exclusive within block
  if (tid == 255) bsum[blockIdx.x] = s[255];
}

__global__ void scan2_kernel(const int* __restrict__ bsum, int* __restrict__ boff, int nb) {
  __shared__ int s[512];
  int tid = threadIdx.x;
  int v = tid < nb ? bsum[tid] : 0;
  s[tid] = v;
  __syncthreads();
  for (int o = 1; o < 512; o <<= 1) {
    int t = tid >= o ? s[tid - o] : 0;
    __syncthreads();
    s[tid] += t;
    __syncthreads();
  }
  if (tid < nb) boff[tid] = s[tid] - v;
}

__global__ void scan3_kernel(int* __restrict__ off, const int* __restrict__ boff,
                             int* __restrict__ cursor, int n, int E) {
  int gid = blockIdx.x * 256 + threadIdx.x;
  if (gid < n) {
    int v = off[gid] + boff[gid >> 8];
    off[gid] = v;
    cursor[gid] = v;
  }
  if (gid == 0) off[n] = E;
}

__global__ void fill_kernel(const int* __restrict__ src, const int* __restrict__ dst,
                            const float* __restrict__ dinv, int* __restrict__ cursor,
                            int* __restrict__ csr_s, float* __restrict__ csr_w, int E) {
  int e = blockIdx.x * blockDim.x + threadIdx.x;
  if (e >= E) return;
  int d = dst[e], s = src[e];
  int p = atomicAdd(&cursor[d], 1);
  csr_s[p] = s;
  csr_w[p] = dinv[s] * dinv[d];
}

// W [K][384] row-major -> Wt [384][K] bf16
__global__ void wt_kernel(const float* __restrict__ W, unsigned short* __restrict__ Wt, int K) {
  int idx = blockIdx.x * blockDim.x + threadIdx.x;
  if (idx >= K * DIMS) return;
  int k = idx / DIMS, nn = idx - k * DIMS;
  Wt[nn * K + k] = f2bf(W[idx]);
}

// ---------------- GEMM: H[M][384] = A[M][K] @ W[K][384] via bf16 MFMA ----------------
// BM=128, BN=384 (full width, A read once), BK=32. 8 waves, each 64x96.
// LDS is fragment-ordered: granule g=[block16][kq][r] so fragment read = base+lane*16
// (conflict-free) and global_load_lds (linear dest, per-lane decoded source) applies.
// LAYER 1: A = x (f32->bf16 in staging). LAYER 2: k<384 leaky(x) f32->bf16; k>=384
// from YBL (bf16 already leaky'd) via global_load_lds.

template <int LAYER>
__launch_bounds__(512, 2)
__global__ void gemm_kernel(const float* __restrict__ X, const unsigned short* __restrict__ YBL,
                            const unsigned short* __restrict__ Wt, float* __restrict__ H,
                            int M, int K) {
  __shared__ unsigned short As[512 * 8];   // 512 granules (128 rows x 4 kq)  8 KB
  __shared__ unsigned short Bs[1536 * 8];  // 1536 granules (384 cols x 4 kq) 24 KB
  const int tid = threadIdx.x;
  const int lane = tid & 63;
  const int wave = tid >> 6;
  const int row0 = blockIdx.x * 128;
  const int fr = lane & 15;
  const int wrb = (wave >> 2) * 4;  // A rowblock base (4 blocks of 16 rows)
  const int wcb = (wave & 3) * 6;   // B colblock base (6 blocks of 16 cols)
  // A f32 reg-staging assignment
  const int arow = tid >> 2;
  const int aq = tid & 3;
  const int ag = ((arow >> 4) << 6) + (aq << 4) + (arow & 15);
  // global_load_lds granule decode (dest granule = linear in tid)
  const int grow_a = ((tid >> 6) << 4) + (tid & 15);  // row for A granule tid
  const int gq_a = (tid >> 4) & 3;

  f32x4 acc[4][6] = {};

  for (int k0 = 0; k0 < K; k0 += 32) {
    __syncthreads();
    // ---- stage B: 3 granules per thread via global_load_lds ----
#pragma unroll
    for (int i = 0; i < 3; i++) {
      const int g = tid + (i << 9);
      const int col = ((g >> 6) << 4) + (g & 15);
      const int q = (g >> 4) & 3;
      GLL16(Wt + (size_t)col * K + k0 + q * 8, &Bs[g * 8]);
    }
    // ---- stage A ----
    if (LAYER == 2 && k0 >= DIMS) {
      // bf16 source, linear-dest global_load_lds (rows>=M read padded garbage: unstored)
      GLL16(YBL + (size_t)(row0 + grow_a) * DIMS + (k0 - DIMS) + gq_a * 8, &As[tid * 8]);
    } else {
      const int grow = row0 + arow;
      float fv[8];
      if (grow < M) {
        const float4* p = (const float4*)(X + (size_t)grow * DIMS + k0 + aq * 8);
        float4 f0 = p[0], f1 = p[1];
        fv[0] = f0.x; fv[1] = f0.y; fv[2] = f0.z; fv[3] = f0.w;
        fv[4] = f1.x; fv[5] = f1.y; fv[6] = f1.z; fv[7] = f1.w;
      } else {
#pragma unroll
        for (int j = 0; j < 8; j++) fv[j] = 0.f;
      }
      u16x8 o;
#pragma unroll
      for (int j = 0; j < 8; j++) {
        float f = fv[j];
        if (LAYER == 2) f = leaky(f);
        o[j] = f2bf(f);
      }
      *(u16x8*)&As[ag * 8] = o;
    }
    __syncthreads();

    s16x8 av[4], bv[6];
#pragma unroll
    for (int m = 0; m < 4; m++) av[m] = *(const s16x8*)&As[((wrb + m) * 64 + lane) * 8];
#pragma unroll
    for (int n = 0; n < 6; n++) bv[n] = *(const s16x8*)&Bs[((wcb + n) * 64 + lane) * 8];
#pragma unroll
    for (int m = 0; m < 4; m++)
#pragma unroll
      for (int n = 0; n < 6; n++)
        acc[m][n] = __builtin_amdgcn_mfma_f32_16x16x32_bf16(av[m], bv[n], acc[m][n], 0, 0, 0);
  }

  // epilogue: D mapping col=lane&15, row=(lane>>4)*4+j
  const int rq = (lane >> 4) * 4;
#pragma unroll
  for (int m = 0; m < 4; m++) {
#pragma unroll
    for (int n = 0; n < 6; n++) {
      const int col = (wcb + n) * 16 + fr;
#pragma unroll
      for (int j = 0; j < 4; j++) {
        const int row = row0 + (wrb + m) * 16 + rq + j;
        if (row < M) H[(size_t)row * DIMS + col] = acc[m][n][j];
      }
    }
  }
}

// ---------------- aggregation: out[i] = bias + dinv[i]^2*H[i] + sum_in w*H[src] --------
// MODE 1: write bf16 with leaky (layer-1 y buffer). MODE 2: write f32 raw (z_pre).

template <int MODE>
__global__ void agg_kernel(const float* __restrict__ H, const float* __restrict__ bias,
                           const float* __restrict__ dinv, const int* __restrict__ off,
                           const int* __restrict__ csr_s, const float* __restrict__ csr_w,
                           void* __restrict__ outp, int n) {
  const int wid = (blockIdx.x * blockDim.x + threadIdx.x) >> 6;
  const int lane = threadIdx.x & 63;
  if (wid >= n) return;
  const float ds = dinv[wid];
  const float ws = ds * ds;
  const float* hr = H + (size_t)wid * DIMS;
  float acc[6];
#pragma unroll
  for (int j = 0; j < 6; j++) acc[j] = bias[lane + 64 * j] + ws * hr[lane + 64 * j];
  const int e1 = off[wid + 1];
  for (int e = off[wid]; e < e1; e++) {
    const int s = csr_s[e];
    const float w = csr_w[e];
    const float* hs = H + (size_t)s * DIMS;
#pragma unroll
    for (int j = 0; j < 6; j++) acc[j] += w * hs[lane + 64 * j];
  }
  if (MODE == 1) {
    unsigned short* o = (unsigned short*)outp + (size_t)wid * DIMS;
#pragma unroll
    for (int j = 0; j < 6; j++) o[lane + 64 * j] = f2bf(leaky(acc[j]));
  } else {
    float* o = (float*)outp + (size_t)wid * DIMS;
#pragma unroll
    for (int j = 0; j < 6; j++) o[lane + 64 * j] = acc[j];
  }
}

// ---------------- finalize: z = leaky(z_pre) in place; a = z @ Wp + bp ----------------

__global__ void final_kernel(float* __restrict__ Z, const float* __restrict__ Wp,
                             const float* __restrict__ bp, float* __restrict__ A, int n) {
  const int wid = (blockIdx.x * blockDim.x + threadIdx.x) >> 6;
  const int lane = threadIdx.x & 63;
  if (wid >= n) return;
  float* zr = Z + (size_t)wid * DIMS;
  float dot = 0.f;
#pragma unroll
  for (int j = 0; j < 6; j++) {
    float f = leaky(zr[lane + 64 * j]);
    zr[lane + 64 * j] = f;
    dot += f * Wp[lane + 64 * j];
  }
#pragma unroll
  for (int o = 32; o > 0; o >>= 1) dot += __shfl_xor(dot, o);
  if (lane == 0) A[wid] = dot + bp[0];
}

// ---------------- launch ----------------

extern "C" void kernel_launch(void* const* d_in, const int* in_sizes, int n_in,
                              void* d_out, int out_size, void* d_ws, size_t ws_size,
                              hipStream_t stream) {
  const float* x = (const float*)d_in[0];
  const int* ei = (const int*)d_in[1];
  const float* W1 = (const float*)d_in[2];
  const float* b1 = (const float*)d_in[3];
  const float* W2 = (const float*)d_in[4];
  const float* b2 = (const float*)d_in[5];
  const float* Wp = (const float*)d_in[6];
  const float* bp = (const float*)d_in[7];
  const int N = in_sizes[0] / DIMS;  // 100000
  const int E = in_sizes[1] / 2;     // 400000
  const int* src = ei;
  const int* dst = ei + E;

  char* p = (char*)d_ws;
  auto alloc = [&](size_t bytes) {
    char* r = p;
    p += (bytes + 255) & ~(size_t)255;
    return r;
  };
  float* h = (float*)alloc((size_t)N * DIMS * 4);  // h1, reused as h2
  unsigned short* ybl = (unsigned short*)alloc((size_t)(N + 128) * DIMS * 2);  // leaky(y) bf16, padded rows
  float* dinv = (float*)alloc((size_t)N * 4);
  int* cnt = (int*)alloc((size_t)N * 4);
  int* off = (int*)alloc((size_t)(N + 1) * 4);
  int* cursor = (int*)alloc((size_t)N * 4);
  int* bsum = (int*)alloc(4096);
  int* boff = (int*)alloc(4096);
  int* csr_s = (int*)alloc((size_t)E * 4);
  float* csr_w = (float*)alloc((size_t)E * 4);
  unsigned short* Wt1 = (unsigned short*)alloc((size_t)DIMS * DIMS * 2);
  unsigned short* Wt2 = (unsigned short*)alloc((size_t)DIMS * 2 * DIMS * 2);

  float* z = (float*)d_out;
  float* a = z + (size_t)N * DIMS;

  const int nbN = (N + 255) / 256;
  const int nbE = (E + 255) / 256;

  hipMemsetAsync(cnt, 0, (size_t)N * 4, stream);
  count_kernel<<<nbE, 256, 0, stream>>>(dst, cnt, E);
  dinv_kernel<<<nbN, 256, 0, stream>>>(cnt, dinv, N);
  scan1_kernel<<<nbN, 256, 0, stream>>>(cnt, off, bsum, N);
  scan2_kernel<<<1, 512, 0, stream>>>(bsum, boff, nbN);
  scan3_kernel<<<nbN, 256, 0, stream>>>(off, boff, cursor, N, E);
  fill_kernel<<<nbE, 256, 0, stream>>>(src, dst, dinv, cursor, csr_s, csr_w, E);
  wt_kernel<<<(DIMS * DIMS + 255) / 256, 256, 0, stream>>>(W1, Wt1, DIMS);
  wt_kernel<<<(2 * DIMS * DIMS + 255) / 256, 256, 0, stream>>>(W2, Wt2, 2 * DIMS);

  const int gx = (N + 127) / 128;
  gemm_kernel<1><<<gx, 512, 0, stream>>>(x, nullptr, Wt1, h, N, DIMS);
  agg_kernel<1><<<(N + 3) / 4, 256, 0, stream>>>(h, b1, dinv, off, csr_s, csr_w, ybl, N);
  gemm_kernel<2><<<gx, 512, 0, stream>>>(x, ybl, Wt2, h, N, 2 * DIMS);
  agg_kernel<2><<<(N + 3) / 4, 256, 0, stream>>>(h, b2, dinv, off, csr_s, csr_w, z, N);
  final_kernel<<<(N + 3) / 4, 256, 0, stream>>>(z, Wp, bp, a, N);
}

// Round 3
// 486.005 us; speedup vs baseline: 1.3589x; 1.3589x over previous
//
#include <hip/hip_runtime.h>

#define DIMS 384
#define SLOPE 0.01f

typedef __attribute__((ext_vector_type(8))) short s16x8;
typedef __attribute__((ext_vector_type(8))) unsigned short u16x8;
typedef __attribute__((ext_vector_type(4))) float f32x4;

typedef __attribute__((address_space(1))) const void gld_src_t;
typedef __attribute__((address_space(3))) void lds_dst_t;
#define GLL16(g, l) __builtin_amdgcn_global_load_lds((gld_src_t*)(g), (lds_dst_t*)(l), 16, 0, 0)

__device__ __forceinline__ unsigned short f2bf(float f) {
  unsigned u = __float_as_uint(f);
  unsigned r = (u + 0x7FFFu + ((u >> 16) & 1u)) >> 16;
  return (unsigned short)r;
}

__device__ __forceinline__ float bf2f(unsigned short u) {
  return __uint_as_float((unsigned)u << 16);
}

__device__ __forceinline__ float leaky(float f) { return f >= 0.f ? f : SLOPE * f; }

// ---------------- graph preprocessing ----------------

__global__ void count_kernel(const int* __restrict__ dst, int* __restrict__ cnt, int E) {
  int e = blockIdx.x * blockDim.x + threadIdx.x;
  if (e < E) atomicAdd(&cnt[dst[e]], 1);
}

__global__ void dinv_kernel(const int* __restrict__ cnt, float* __restrict__ dinv, int n) {
  int i = blockIdx.x * blockDim.x + threadIdx.x;
  if (i < n) dinv[i] = 1.0f / sqrtf((float)(cnt[i] + 1));  // +1 self loop
}

__global__ void scan1_kernel(const int* __restrict__ cnt, int* __restrict__ off,
                             int* __restrict__ bsum, int n) {
  __shared__ int s[256];
  int tid = threadIdx.x, gid = blockIdx.x * 256 + tid;
  int v = gid < n ? cnt[gid] : 0;
  s[tid] = v;
  __syncthreads();
  for (int o = 1; o < 256; o <<= 1) {
    int t = tid >= o ? s[tid - o] : 0;
    __syncthreads();
    s[tid] += t;
    __syncthreads();
  }
  if (gid < n) off[gid] = s[tid] - v;  // exclusive within block
  if (tid == 255) bsum[blockIdx.x] = s[255];
}

__global__ void scan2_kernel(const int* __restrict__ bsum, int* __restrict__ boff, int nb) {
  __shared__ int s[512];
  int tid = threadIdx.x;
  int v = tid < nb ? bsum[tid] : 0;
  s[tid] = v;
  __syncthreads();
  for (int o = 1; o < 512; o <<= 1) {
    int t = tid >= o ? s[tid - o] : 0;
    __syncthreads();
    s[tid] += t;
    __syncthreads();
  }
  if (tid < nb) boff[tid] = s[tid] - v;
}

__global__ void scan3_kernel(int* __restrict__ off, const int* __restrict__ boff,
                             int* __restrict__ cursor, int n, int E) {
  int gid = blockIdx.x * 256 + threadIdx.x;
  if (gid < n) {
    int v = off[gid] + boff[gid >> 8];
    off[gid] = v;
    cursor[gid] = v;
  }
  if (gid == 0) off[n] = E;
}

__global__ void fill_kernel(const int* __restrict__ src, const int* __restrict__ dst,
                            const float* __restrict__ dinv, int* __restrict__ cursor,
                            int* __restrict__ csr_s, float* __restrict__ csr_w, int E) {
  int e = blockIdx.x * blockDim.x + threadIdx.x;
  if (e >= E) return;
  int d = dst[e], s = src[e];
  int p = atomicAdd(&cursor[d], 1);
  csr_s[p] = s;
  csr_w[p] = dinv[s] * dinv[d];
}

// W [K][384] row-major -> Wt [384][K] bf16
__global__ void wt_kernel(const float* __restrict__ W, unsigned short* __restrict__ Wt, int K) {
  int idx = blockIdx.x * blockDim.x + threadIdx.x;
  if (idx >= K * DIMS) return;
  int k = idx / DIMS, nn = idx - k * DIMS;
  Wt[nn * K + k] = f2bf(W[idx]);
}

// X f32 -> Xb (bf16 raw) + XbL (bf16 leaky)
__global__ void xprep_kernel(const float* __restrict__ X, unsigned short* __restrict__ Xb,
                             unsigned short* __restrict__ XbL, int total8) {
  int i = blockIdx.x * blockDim.x + threadIdx.x;
  if (i >= total8) return;
  const float4* p = (const float4*)(X + (size_t)i * 8);
  float4 a = p[0], b = p[1];
  float f[8] = {a.x, a.y, a.z, a.w, b.x, b.y, b.z, b.w};
  u16x8 r, l;
#pragma unroll
  for (int j = 0; j < 8; j++) {
    r[j] = f2bf(f[j]);
    l[j] = f2bf(leaky(f[j]));
  }
  *(u16x8*)(Xb + (size_t)i * 8) = r;
  *(u16x8*)(XbL + (size_t)i * 8) = l;
}

// ---------------- GEMM (m97 structure): H[M][384] = A[M][K] @ W[K][384] ----------------
// BM=BN=128, BK=64, 256 threads / 4 waves, each wave 64x64 (4x4 16x16x32 frags).
// LDS linear [row][64] bf16; both operands staged via global_load_lds width=16
// (fully coalesced: 8 lanes x 16B per 128B row). 2-barrier K-loop.
// LAYER 1: A = Xb,  H out bf16.  LAYER 2: A = XbL (k<384) / YBL (k>=384), H out f32.

template <int LAYER>
__launch_bounds__(256, 4)
__global__ void gemm_kernel(const unsigned short* __restrict__ A1,
                            const unsigned short* __restrict__ A2,
                            const unsigned short* __restrict__ Wt,
                            void* __restrict__ Hout, int M, int K) {
  __shared__ unsigned short As[128 * 64];  // 16 KB
  __shared__ unsigned short Bs[128 * 64];  // 16 KB
  const int tid = threadIdx.x;
  const int lane = tid & 63;
  const int wave = tid >> 6;
  const int wr = (wave >> 1) * 64;
  const int wc = (wave & 1) * 64;
  const int row0 = blockIdx.x * 128;
  const int n0 = blockIdx.y * 128;
  const int fr = lane & 15;
  const int kq = (lane >> 4) * 8;  // element offset within 32-k step

  f32x4 acc[4][4] = {};

  for (int k0 = 0; k0 < K; k0 += 64) {
    __syncthreads();
    const unsigned short* Asrc;
    int ka;
    if (LAYER == 2 && k0 >= DIMS) {
      Asrc = A2;
      ka = k0 - DIMS;
    } else {
      Asrc = A1;
      ka = k0;
    }
#pragma unroll
    for (int i = 0; i < 4; i++) {
      const int g = i * 256 + tid;
      const int r = g >> 3;
      const int c = (g & 7) * 8;
      GLL16(Asrc + (size_t)(row0 + r) * DIMS + ka + c, &As[g * 8]);
    }
#pragma unroll
    for (int i = 0; i < 4; i++) {
      const int g = i * 256 + tid;
      const int r = g >> 3;
      const int c = (g & 7) * 8;
      GLL16(Wt + (size_t)(n0 + r) * K + k0 + c, &Bs[g * 8]);
    }
    __syncthreads();

#pragma unroll
    for (int h = 0; h < 2; h++) {
      s16x8 av[4], bv[4];
#pragma unroll
      for (int m = 0; m < 4; m++)
        av[m] = *(const s16x8*)&As[(wr + m * 16 + fr) * 64 + h * 32 + kq];
#pragma unroll
      for (int n = 0; n < 4; n++)
        bv[n] = *(const s16x8*)&Bs[(wc + n * 16 + fr) * 64 + h * 32 + kq];
#pragma unroll
      for (int m = 0; m < 4; m++)
#pragma unroll
        for (int n = 0; n < 4; n++)
          acc[m][n] = __builtin_amdgcn_mfma_f32_16x16x32_bf16(av[m], bv[n], acc[m][n], 0, 0, 0);
    }
  }

  // epilogue: D mapping col=lane&15, row=(lane>>4)*4+j
  const int rq = (lane >> 4) * 4;
#pragma unroll
  for (int m = 0; m < 4; m++) {
#pragma unroll
    for (int n = 0; n < 4; n++) {
      const int col = n0 + wc + n * 16 + fr;
#pragma unroll
      for (int j = 0; j < 4; j++) {
        const int row = row0 + wr + m * 16 + rq + j;
        if (row < M) {
          if (LAYER == 1)
            ((unsigned short*)Hout)[(size_t)row * DIMS + col] = f2bf(acc[m][n][j]);
          else
            ((float*)Hout)[(size_t)row * DIMS + col] = acc[m][n][j];
        }
      }
    }
  }
}

// ---------------- agg1: y = leaky(bias + dinv^2*H1 + sum w*H1[src]) -> bf16 ----------

__global__ void agg1_kernel(const unsigned short* __restrict__ H, const float* __restrict__ bias,
                            const float* __restrict__ dinv, const int* __restrict__ off,
                            const int* __restrict__ csr_s, const float* __restrict__ csr_w,
                            unsigned short* __restrict__ Y, int n) {
  const int wid = (blockIdx.x * blockDim.x + threadIdx.x) >> 6;
  const int lane = threadIdx.x & 63;
  if (wid >= n) return;
  const float ds = dinv[wid];
  const float ws = ds * ds;
  const unsigned short* hr = H + (size_t)wid * DIMS;
  float acc[6];
#pragma unroll
  for (int j = 0; j < 3; j++) {
    const int d = 2 * lane + 128 * j;
    unsigned v = *(const unsigned*)(hr + d);
    acc[2 * j] = bias[d] + ws * bf2f((unsigned short)v);
    acc[2 * j + 1] = bias[d + 1] + ws * bf2f((unsigned short)(v >> 16));
  }
  const int e1 = off[wid + 1];
  for (int e = off[wid]; e < e1; e++) {
    const int s = csr_s[e];
    const float w = csr_w[e];
    const unsigned short* hs = H + (size_t)s * DIMS;
#pragma unroll
    for (int j = 0; j < 3; j++) {
      unsigned v = *(const unsigned*)(hs + 2 * lane + 128 * j);
      acc[2 * j] += w * bf2f((unsigned short)v);
      acc[2 * j + 1] += w * bf2f((unsigned short)(v >> 16));
    }
  }
  unsigned short* o = Y + (size_t)wid * DIMS;
#pragma unroll
  for (int j = 0; j < 3; j++) {
    unsigned lo = f2bf(leaky(acc[2 * j]));
    unsigned hi = f2bf(leaky(acc[2 * j + 1]));
    *(unsigned*)(o + 2 * lane + 128 * j) = lo | (hi << 16);
  }
}

// ---------------- agg2 (+fused pooler): z = leaky(bias + dinv^2*H2 + sum w*H2[src]);
//                   a = z @ Wp + bp ----------------

__global__ void agg2_kernel(const float* __restrict__ H, const float* __restrict__ bias,
                            const float* __restrict__ dinv, const int* __restrict__ off,
                            const int* __restrict__ csr_s, const float* __restrict__ csr_w,
                            float* __restrict__ Z, const float* __restrict__ Wp,
                            const float* __restrict__ bp, float* __restrict__ A, int n) {
  const int wid = (blockIdx.x * blockDim.x + threadIdx.x) >> 6;
  const int lane = threadIdx.x & 63;
  if (wid >= n) return;
  const float ds = dinv[wid];
  const float ws = ds * ds;
  const float2* hr = (const float2*)(H + (size_t)wid * DIMS);
  float acc[6];
#pragma unroll
  for (int j = 0; j < 3; j++) {
    const int d = 2 * (lane + 64 * j);
    float2 v = hr[lane + 64 * j];
    acc[2 * j] = bias[d] + ws * v.x;
    acc[2 * j + 1] = bias[d + 1] + ws * v.y;
  }
  const int e1 = off[wid + 1];
  for (int e = off[wid]; e < e1; e++) {
    const int s = csr_s[e];
    const float w = csr_w[e];
    const float2* hs = (const float2*)(H + (size_t)s * DIMS);
#pragma unroll
    for (int j = 0; j < 3; j++) {
      float2 v = hs[lane + 64 * j];
      acc[2 * j] += w * v.x;
      acc[2 * j + 1] += w * v.y;
    }
  }
  float2* zr = (float2*)(Z + (size_t)wid * DIMS);
  float dot = 0.f;
#pragma unroll
  for (int j = 0; j < 3; j++) {
    float z0 = leaky(acc[2 * j]);
    float z1 = leaky(acc[2 * j + 1]);
    float2 wp = ((const float2*)Wp)[lane + 64 * j];
    zr[lane + 64 * j] = make_float2(z0, z1);
    dot += z0 * wp.x + z1 * wp.y;
  }
#pragma unroll
  for (int o = 32; o > 0; o >>= 1) dot += __shfl_xor(dot, o);
  if (lane == 0) A[wid] = dot + bp[0];
}

// ---------------- launch ----------------

extern "C" void kernel_launch(void* const* d_in, const int* in_sizes, int n_in,
                              void* d_out, int out_size, void* d_ws, size_t ws_size,
                              hipStream_t stream) {
  const float* x = (const float*)d_in[0];
  const int* ei = (const int*)d_in[1];
  const float* W1 = (const float*)d_in[2];
  const float* b1 = (const float*)d_in[3];
  const float* W2 = (const float*)d_in[4];
  const float* b2 = (const float*)d_in[5];
  const float* Wp = (const float*)d_in[6];
  const float* bp = (const float*)d_in[7];
  const int N = in_sizes[0] / DIMS;  // 100000
  const int E = in_sizes[1] / 2;     // 400000
  const int* src = ei;
  const int* dst = ei + E;
  const int NP = N + 128;  // row-padded

  char* p = (char*)d_ws;
  auto alloc = [&](size_t bytes) {
    char* r = p;
    p += (bytes + 255) & ~(size_t)255;
    return r;
  };
  // RegionA: [ Xb bf16 (NP rows) | H1 bf16 (NP rows) ]; reused as H2 f32 (N rows) later.
  // Hazard check: Xb dead after gemm1; H1 dead after agg1; gemm2 writes H2 over both.
  char* regionA = alloc(2 * (size_t)NP * DIMS * 2);
  unsigned short* Xb = (unsigned short*)regionA;
  unsigned short* H1 = (unsigned short*)(regionA + (size_t)NP * DIMS * 2);
  float* H2 = (float*)regionA;
  unsigned short* XbL = (unsigned short*)alloc((size_t)NP * DIMS * 2);
  unsigned short* YBL = (unsigned short*)alloc((size_t)NP * DIMS * 2);
  float* dinv = (float*)alloc((size_t)N * 4);
  int* cnt = (int*)alloc((size_t)N * 4);
  int* off = (int*)alloc((size_t)(N + 1) * 4);
  int* cursor = (int*)alloc((size_t)N * 4);
  int* bsum = (int*)alloc(4096);
  int* boff = (int*)alloc(4096);
  int* csr_s = (int*)alloc((size_t)E * 4);
  float* csr_w = (float*)alloc((size_t)E * 4);
  unsigned short* Wt1 = (unsigned short*)alloc((size_t)DIMS * DIMS * 2);
  unsigned short* Wt2 = (unsigned short*)alloc((size_t)DIMS * 2 * DIMS * 2);

  float* z = (float*)d_out;
  float* a = z + (size_t)N * DIMS;

  const int nbN = (N + 255) / 256;
  const int nbE = (E + 255) / 256;

  hipMemsetAsync(cnt, 0, (size_t)N * 4, stream);
  count_kernel<<<nbE, 256, 0, stream>>>(dst, cnt, E);
  dinv_kernel<<<nbN, 256, 0, stream>>>(cnt, dinv, N);
  scan1_kernel<<<nbN, 256, 0, stream>>>(cnt, off, bsum, N);
  scan2_kernel<<<1, 512, 0, stream>>>(bsum, boff, nbN);
  scan3_kernel<<<nbN, 256, 0, stream>>>(off, boff, cursor, N, E);
  fill_kernel<<<nbE, 256, 0, stream>>>(src, dst, dinv, cursor, csr_s, csr_w, E);
  wt_kernel<<<(DIMS * DIMS + 255) / 256, 256, 0, stream>>>(W1, Wt1, DIMS);
  wt_kernel<<<(2 * DIMS * DIMS + 255) / 256, 256, 0, stream>>>(W2, Wt2, 2 * DIMS);
  const int total8 = N * DIMS / 8;
  xprep_kernel<<<(total8 + 255) / 256, 256, 0, stream>>>(x, Xb, XbL, total8);

  dim3 gg((N + 127) / 128, DIMS / 128);
  gemm_kernel<1><<<gg, 256, 0, stream>>>(Xb, nullptr, Wt1, H1, N, DIMS);
  agg1_kernel<<<(N + 3) / 4, 256, 0, stream>>>(H1, b1, dinv, off, csr_s, csr_w, YBL, N);
  gemm_kernel<2><<<gg, 256, 0, stream>>>(XbL, YBL, Wt2, H2, N, 2 * DIMS);
  agg2_kernel<<<(N + 3) / 4, 256, 0, stream>>>(H2, b2, dinv, off, csr_s, csr_w, z, Wp, bp, a, N);
}

// Round 4
// 421.440 us; speedup vs baseline: 1.5671x; 1.1532x over previous
//
#include <hip/hip_runtime.h>

#define DIMS 384
#define SLOPE 0.01f

typedef __attribute__((ext_vector_type(8))) short s16x8;
typedef __attribute__((ext_vector_type(8))) unsigned short u16x8;
typedef __attribute__((ext_vector_type(4))) float f32x4;
typedef __attribute__((ext_vector_type(2))) float f32x2;

typedef __attribute__((address_space(1))) const void gld_src_t;
typedef __attribute__((address_space(3))) void lds_dst_t;
#define GLL16(g, l) __builtin_amdgcn_global_load_lds((gld_src_t*)(g), (lds_dst_t*)(l), 16, 0, 0)

__device__ __forceinline__ unsigned short f2bf(float f) {
  unsigned u = __float_as_uint(f);
  unsigned r = (u + 0x7FFFu + ((u >> 16) & 1u)) >> 16;
  return (unsigned short)r;
}

__device__ __forceinline__ float bf2f(unsigned short u) {
  return __uint_as_float((unsigned)u << 16);
}

__device__ __forceinline__ float leaky(float f) { return f >= 0.f ? f : SLOPE * f; }

// ---------------- graph preprocessing ----------------

__global__ void count_kernel(const int* __restrict__ dst, int* __restrict__ cnt, int E) {
  int e = blockIdx.x * blockDim.x + threadIdx.x;
  if (e < E) atomicAdd(&cnt[dst[e]], 1);
}

// dinv + CSR segment reservation (atomic; segment order run-varying but each
// node's segment contiguous -> per-node sums identical up to fp order, which
// fill's atomics already made nondeterministic; validation is tolerance-based)
__global__ void node_prep_kernel(const int* __restrict__ cnt, int* __restrict__ tot,
                                 float* __restrict__ dinv, int* __restrict__ off,
                                 int* __restrict__ cursor, int n) {
  int i = blockIdx.x * blockDim.x + threadIdx.x;
  if (i >= n) return;
  int c = cnt[i];
  dinv[i] = 1.0f / sqrtf((float)(c + 1));  // +1 self loop
  int o = atomicAdd(tot, c);
  off[i] = o;
  cursor[i] = o;
}

__global__ void fill_kernel(const int* __restrict__ src, const int* __restrict__ dst,
                            const float* __restrict__ dinv, int* __restrict__ cursor,
                            int* __restrict__ csr_s, float* __restrict__ csr_w, int E) {
  int e = blockIdx.x * blockDim.x + threadIdx.x;
  if (e >= E) return;
  int d = dst[e], s = src[e];
  int p = atomicAdd(&cursor[d], 1);
  csr_s[p] = s;
  csr_w[p] = dinv[s] * dinv[d];
}

// W [K][384] row-major -> Wt [384][K] bf16
__global__ void wt_kernel(const float* __restrict__ W, unsigned short* __restrict__ Wt, int K) {
  int idx = blockIdx.x * blockDim.x + threadIdx.x;
  if (idx >= K * DIMS) return;
  int k = idx / DIMS, nn = idx - k * DIMS;
  Wt[nn * K + k] = f2bf(W[idx]);
}

// X f32 -> Xb (bf16 raw) + XbL (bf16 leaky)
__global__ void xprep_kernel(const float* __restrict__ X, unsigned short* __restrict__ Xb,
                             unsigned short* __restrict__ XbL, int total8) {
  int i = blockIdx.x * blockDim.x + threadIdx.x;
  if (i >= total8) return;
  const float4* p = (const float4*)(X + (size_t)i * 8);
  float4 a = p[0], b = p[1];
  float f[8] = {a.x, a.y, a.z, a.w, b.x, b.y, b.z, b.w};
  u16x8 r, l;
#pragma unroll
  for (int j = 0; j < 8; j++) {
    r[j] = f2bf(f[j]);
    l[j] = f2bf(leaky(f[j]));
  }
  *(u16x8*)(Xb + (size_t)i * 8) = r;
  *(u16x8*)(XbL + (size_t)i * 8) = l;
}

// ---------------- GEMM (m97 structure): H[M][384] = A[M][K] @ W[K][384] ----------------
// BM=BN=128, BK=64, 256 threads / 4 waves, each wave 64x64 (4x4 16x16x32 frags).
// LDS linear [row][64] bf16; both operands staged via global_load_lds width=16.
// Output H is bf16 for both layers.
// LAYER 1: A = Xb.  LAYER 2: A = XbL (k<384) / YBL (k>=384).

template <int LAYER>
__launch_bounds__(256, 4)
__global__ void gemm_kernel(const unsigned short* __restrict__ A1,
                            const unsigned short* __restrict__ A2,
                            const unsigned short* __restrict__ Wt,
                            unsigned short* __restrict__ Hout, int M, int K) {
  __shared__ unsigned short As[128 * 64];  // 16 KB
  __shared__ unsigned short Bs[128 * 64];  // 16 KB
  const int tid = threadIdx.x;
  const int lane = tid & 63;
  const int wave = tid >> 6;
  const int wr = (wave >> 1) * 64;
  const int wc = (wave & 1) * 64;
  const int row0 = blockIdx.x * 128;
  const int n0 = blockIdx.y * 128;
  const int fr = lane & 15;
  const int kq = (lane >> 4) * 8;  // element offset within 32-k step

  f32x4 acc[4][4] = {};

  for (int k0 = 0; k0 < K; k0 += 64) {
    __syncthreads();
    const unsigned short* Asrc;
    int ka;
    if (LAYER == 2 && k0 >= DIMS) {
      Asrc = A2;
      ka = k0 - DIMS;
    } else {
      Asrc = A1;
      ka = k0;
    }
#pragma unroll
    for (int i = 0; i < 4; i++) {
      const int g = i * 256 + tid;
      const int r = g >> 3;
      const int c = (g & 7) * 8;
      GLL16(Asrc + (size_t)(row0 + r) * DIMS + ka + c, &As[g * 8]);
    }
#pragma unroll
    for (int i = 0; i < 4; i++) {
      const int g = i * 256 + tid;
      const int r = g >> 3;
      const int c = (g & 7) * 8;
      GLL16(Wt + (size_t)(n0 + r) * K + k0 + c, &Bs[g * 8]);
    }
    __syncthreads();

#pragma unroll
    for (int h = 0; h < 2; h++) {
      s16x8 av[4], bv[4];
#pragma unroll
      for (int m = 0; m < 4; m++)
        av[m] = *(const s16x8*)&As[(wr + m * 16 + fr) * 64 + h * 32 + kq];
#pragma unroll
      for (int n = 0; n < 4; n++)
        bv[n] = *(const s16x8*)&Bs[(wc + n * 16 + fr) * 64 + h * 32 + kq];
#pragma unroll
      for (int m = 0; m < 4; m++)
#pragma unroll
        for (int n = 0; n < 4; n++)
          acc[m][n] = __builtin_amdgcn_mfma_f32_16x16x32_bf16(av[m], bv[n], acc[m][n], 0, 0, 0);
    }
  }

  // epilogue: D mapping col=lane&15, row=(lane>>4)*4+j
  const int rq = (lane >> 4) * 4;
#pragma unroll
  for (int m = 0; m < 4; m++) {
#pragma unroll
    for (int n = 0; n < 4; n++) {
      const int col = n0 + wc + n * 16 + fr;
#pragma unroll
      for (int j = 0; j < 4; j++) {
        const int row = row0 + wr + m * 16 + rq + j;
        if (row < M) Hout[(size_t)row * DIMS + col] = f2bf(acc[m][n][j]);
      }
    }
  }
}

// ---------------- aggregation: acc = bias + dinv^2*H[i] + sum_in w*H[src], H bf16 ------
// MODE 1: out = bf16 leaky (layer-1 y). MODE 2: out = f32 z, + fused pooler a.
// Edge loop software-pipelined 2-wide: 6 independent gather loads in flight.

template <int MODE>
__global__ void agg_kernel(const unsigned short* __restrict__ H, const float* __restrict__ bias,
                           const float* __restrict__ dinv, const int* __restrict__ off,
                           const int* __restrict__ cnt, const int* __restrict__ csr_s,
                           const float* __restrict__ csr_w, void* __restrict__ outp,
                           const float* __restrict__ Wp, const float* __restrict__ bp,
                           float* __restrict__ A, int n) {
  const int wid = (blockIdx.x * blockDim.x + threadIdx.x) >> 6;
  const int lane = threadIdx.x & 63;
  if (wid >= n) return;
  const float ds = dinv[wid];
  const float ws = ds * ds;
  const unsigned short* hr = H + (size_t)wid * DIMS;
  float acc[6];
#pragma unroll
  for (int j = 0; j < 3; j++) {
    const int d = 2 * lane + 128 * j;
    unsigned v = *(const unsigned*)(hr + d);
    acc[2 * j] = bias[d] + ws * bf2f((unsigned short)v);
    acc[2 * j + 1] = bias[d + 1] + ws * bf2f((unsigned short)(v >> 16));
  }
  const int e0 = off[wid];
  const int e1 = e0 + cnt[wid];
  int e = e0;
  for (; e + 2 <= e1; e += 2) {
    const int sA = csr_s[e], sB = csr_s[e + 1];
    const float wA = csr_w[e], wB = csr_w[e + 1];
    const unsigned short* hA = H + (size_t)sA * DIMS;
    const unsigned short* hB = H + (size_t)sB * DIMS;
    unsigned vA[3], vB[3];
#pragma unroll
    for (int j = 0; j < 3; j++) vA[j] = *(const unsigned*)(hA + 2 * lane + 128 * j);
#pragma unroll
    for (int j = 0; j < 3; j++) vB[j] = *(const unsigned*)(hB + 2 * lane + 128 * j);
#pragma unroll
    for (int j = 0; j < 3; j++) {
      acc[2 * j] += wA * bf2f((unsigned short)vA[j]);
      acc[2 * j + 1] += wA * bf2f((unsigned short)(vA[j] >> 16));
      acc[2 * j] += wB * bf2f((unsigned short)vB[j]);
      acc[2 * j + 1] += wB * bf2f((unsigned short)(vB[j] >> 16));
    }
  }
  if (e < e1) {
    const int s = csr_s[e];
    const float w = csr_w[e];
    const unsigned short* hs = H + (size_t)s * DIMS;
#pragma unroll
    for (int j = 0; j < 3; j++) {
      unsigned v = *(const unsigned*)(hs + 2 * lane + 128 * j);
      acc[2 * j] += w * bf2f((unsigned short)v);
      acc[2 * j + 1] += w * bf2f((unsigned short)(v >> 16));
    }
  }
  if (MODE == 1) {
    unsigned short* o = (unsigned short*)outp + (size_t)wid * DIMS;
#pragma unroll
    for (int j = 0; j < 3; j++) {
      unsigned lo = f2bf(leaky(acc[2 * j]));
      unsigned hi = f2bf(leaky(acc[2 * j + 1]));
      *(unsigned*)(o + 2 * lane + 128 * j) = lo | (hi << 16);
    }
  } else {
    float* Z = (float*)outp + (size_t)wid * DIMS;
    float dot = 0.f;
#pragma unroll
    for (int j = 0; j < 3; j++) {
      float z0 = leaky(acc[2 * j]);
      float z1 = leaky(acc[2 * j + 1]);
      f32x2 wp = *(const f32x2*)(Wp + 2 * lane + 128 * j);
      f32x2 zv = {z0, z1};
      // z is never re-read: nontemporal keeps H resident in LLC
      __builtin_nontemporal_store(zv, (f32x2*)(Z + 2 * lane + 128 * j));
      dot += z0 * wp.x + z1 * wp.y;
    }
#pragma unroll
    for (int o = 32; o > 0; o >>= 1) dot += __shfl_xor(dot, o);
    if (lane == 0) A[wid] = dot + bp[0];
  }
}

// ---------------- launch ----------------

extern "C" void kernel_launch(void* const* d_in, const int* in_sizes, int n_in,
                              void* d_out, int out_size, void* d_ws, size_t ws_size,
                              hipStream_t stream) {
  const float* x = (const float*)d_in[0];
  const int* ei = (const int*)d_in[1];
  const float* W1 = (const float*)d_in[2];
  const float* b1 = (const float*)d_in[3];
  const float* W2 = (const float*)d_in[4];
  const float* b2 = (const float*)d_in[5];
  const float* Wp = (const float*)d_in[6];
  const float* bp = (const float*)d_in[7];
  const int N = in_sizes[0] / DIMS;  // 100000
  const int E = in_sizes[1] / 2;     // 400000
  const int* src = ei;
  const int* dst = ei + E;
  const int NP = N + 128;  // row-padded

  char* p = (char*)d_ws;
  auto alloc = [&](size_t bytes) {
    char* r = p;
    p += (bytes + 255) & ~(size_t)255;
    return r;
  };
  // RegionA: [ Xb bf16 (NP rows) | H1 bf16 (NP rows) ]; H2 (bf16, NP rows) reuses the
  // Xb slot. Hazards: Xb dead after gemm1; H1 dead after agg1; gemm2 writes H2 after both.
  char* regionA = alloc(2 * (size_t)NP * DIMS * 2);
  unsigned short* Xb = (unsigned short*)regionA;
  unsigned short* H1 = (unsigned short*)(regionA + (size_t)NP * DIMS * 2);
  unsigned short* H2 = (unsigned short*)regionA;
  unsigned short* XbL = (unsigned short*)alloc((size_t)NP * DIMS * 2);
  unsigned short* YBL = (unsigned short*)alloc((size_t)NP * DIMS * 2);
  float* dinv = (float*)alloc((size_t)N * 4);
  int* cnt = (int*)alloc((size_t)(N + 1) * 4);
  int* tot = cnt + N;
  int* off = (int*)alloc((size_t)N * 4);
  int* cursor = (int*)alloc((size_t)N * 4);
  int* csr_s = (int*)alloc((size_t)E * 4);
  float* csr_w = (float*)alloc((size_t)E * 4);
  unsigned short* Wt1 = (unsigned short*)alloc((size_t)DIMS * DIMS * 2);
  unsigned short* Wt2 = (unsigned short*)alloc((size_t)DIMS * 2 * DIMS * 2);

  float* z = (float*)d_out;
  float* a = z + (size_t)N * DIMS;

  const int nbN = (N + 255) / 256;
  const int nbE = (E + 255) / 256;

  hipMemsetAsync(cnt, 0, (size_t)(N + 1) * 4, stream);
  count_kernel<<<nbE, 256, 0, stream>>>(dst, cnt, E);
  node_prep_kernel<<<nbN, 256, 0, stream>>>(cnt, tot, dinv, off, cursor, N);
  fill_kernel<<<nbE, 256, 0, stream>>>(src, dst, dinv, cursor, csr_s, csr_w, E);
  wt_kernel<<<(DIMS * DIMS + 255) / 256, 256, 0, stream>>>(W1, Wt1, DIMS);
  wt_kernel<<<(2 * DIMS * DIMS + 255) / 256, 256, 0, stream>>>(W2, Wt2, 2 * DIMS);
  const int total8 = N * DIMS / 8;
  xprep_kernel<<<(total8 + 255) / 256, 256, 0, stream>>>(x, Xb, XbL, total8);

  dim3 gg((N + 127) / 128, DIMS / 128);
  gemm_kernel<1><<<gg, 256, 0, stream>>>(Xb, nullptr, Wt1, H1, N, DIMS);
  agg_kernel<1><<<(N + 3) / 4, 256, 0, stream>>>(H1, b1, dinv, off, cnt, csr_s, csr_w, YBL,
                                                 nullptr, nullptr, nullptr, N);
  gemm_kernel<2><<<gg, 256, 0, stream>>>(XbL, YBL, Wt2, H2, N, 2 * DIMS);
  agg_kernel<2><<<(N + 3) / 4, 256, 0, stream>>>(H2, b2, dinv, off, cnt, csr_s, csr_w, z,
                                                 Wp, bp, a, N);
}

// Round 5
// 416.790 us; speedup vs baseline: 1.5846x; 1.0112x over previous
//
#include <hip/hip_runtime.h>

#define DIMS 384
#define SLOPE 0.01f

typedef __attribute__((ext_vector_type(8))) short s16x8;
typedef __attribute__((ext_vector_type(8))) unsigned short u16x8;
typedef __attribute__((ext_vector_type(4))) float f32x4;
typedef __attribute__((ext_vector_type(2))) float f32x2;

typedef __attribute__((address_space(1))) const void gld_src_t;
typedef __attribute__((address_space(3))) void lds_dst_t;
#define GLL16(g, l) __builtin_amdgcn_global_load_lds((gld_src_t*)(g), (lds_dst_t*)(l), 16, 0, 0)

__device__ __forceinline__ unsigned short f2bf(float f) {
  unsigned u = __float_as_uint(f);
  unsigned r = (u + 0x7FFFu + ((u >> 16) & 1u)) >> 16;
  return (unsigned short)r;
}

__device__ __forceinline__ float bf2f(unsigned short u) {
  return __uint_as_float((unsigned)u << 16);
}

__device__ __forceinline__ float leaky(float f) { return f >= 0.f ? f : SLOPE * f; }

// Bijective XCD-chunk swizzle (guide m204): HW dispatches bid round-robin over 8 XCDs;
// this gives each XCD a CONTIGUOUS run of logical ids. Valid for any nwg.
__device__ __forceinline__ int xcd_swz(int bid, int nwg) {
  const int q = nwg >> 3, r = nwg & 7;
  const int xcd = bid & 7, i = bid >> 3;
  const int base = (xcd < r) ? xcd * (q + 1) : r * (q + 1) + (xcd - r) * q;
  return base + i;
}

// ---------------- graph preprocessing ----------------

__global__ void count_kernel(const int* __restrict__ dst, int* __restrict__ cnt, int E) {
  int e = blockIdx.x * blockDim.x + threadIdx.x;
  if (e < E) atomicAdd(&cnt[dst[e]], 1);
}

// dinv + CSR segment reservation (atomic; segment base order run-varying but each
// node's segment contiguous; validation is tolerance-based)
__global__ void node_prep_kernel(const int* __restrict__ cnt, int* __restrict__ tot,
                                 float* __restrict__ dinv, int* __restrict__ off,
                                 int* __restrict__ cursor, int n) {
  int i = blockIdx.x * blockDim.x + threadIdx.x;
  if (i >= n) return;
  int c = cnt[i];
  dinv[i] = 1.0f / sqrtf((float)(c + 1));  // +1 self loop
  int o = atomicAdd(tot, c);
  off[i] = o;
  cursor[i] = o;
}

__global__ void fill_kernel(const int* __restrict__ src, const int* __restrict__ dst,
                            const float* __restrict__ dinv, int* __restrict__ cursor,
                            int* __restrict__ csr_s, float* __restrict__ csr_w, int E) {
  int e = blockIdx.x * blockDim.x + threadIdx.x;
  if (e >= E) return;
  int d = dst[e], s = src[e];
  int p = atomicAdd(&cursor[d], 1);
  csr_s[p] = s;
  csr_w[p] = dinv[s] * dinv[d];
}

// W [K][384] row-major -> Wt [384][K] bf16
__global__ void wt_kernel(const float* __restrict__ W, unsigned short* __restrict__ Wt, int K) {
  int idx = blockIdx.x * blockDim.x + threadIdx.x;
  if (idx >= K * DIMS) return;
  int k = idx / DIMS, nn = idx - k * DIMS;
  Wt[nn * K + k] = f2bf(W[idx]);
}

// X f32 -> Xb (bf16 raw) + XbL (bf16 leaky)
__global__ void xprep_kernel(const float* __restrict__ X, unsigned short* __restrict__ Xb,
                             unsigned short* __restrict__ XbL, int total8) {
  int i = blockIdx.x * blockDim.x + threadIdx.x;
  if (i >= total8) return;
  const float4* p = (const float4*)(X + (size_t)i * 8);
  float4 a = p[0], b = p[1];
  float f[8] = {a.x, a.y, a.z, a.w, b.x, b.y, b.z, b.w};
  u16x8 r, l;
#pragma unroll
  for (int j = 0; j < 8; j++) {
    r[j] = f2bf(f[j]);
    l[j] = f2bf(leaky(f[j]));
  }
  *(u16x8*)(Xb + (size_t)i * 8) = r;
  *(u16x8*)(XbL + (size_t)i * 8) = l;
}

// ---------------- GEMM (m97 structure): H[M][384] = A[M][K] @ W[K][384] ----------------
// BM=BN=128, BK=64, 256 threads / 4 waves, each wave 64x64 (4x4 16x16x32 frags).
// LDS linear [row][64] bf16; both operands staged via global_load_lds width=16.
// 1D grid, XCD-chunk swizzled; logical order = (row-panel, col) with the 3 col-blocks
// of one A-panel adjacent -> panel re-reads hit same-XCD L2/LLC instead of HBM.
// Output H is bf16 for both layers.
// LAYER 1: A = Xb.  LAYER 2: A = XbL (k<384) / YBL (k>=384).

template <int LAYER>
__launch_bounds__(256, 4)
__global__ void gemm_kernel(const unsigned short* __restrict__ A1,
                            const unsigned short* __restrict__ A2,
                            const unsigned short* __restrict__ Wt,
                            unsigned short* __restrict__ Hout, int M, int K) {
  __shared__ unsigned short As[128 * 64];  // 16 KB
  __shared__ unsigned short Bs[128 * 64];  // 16 KB
  const int logical = xcd_swz(blockIdx.x, gridDim.x);
  const int row0 = (logical / 3) * 128;
  const int n0 = (logical % 3) * 128;
  const int tid = threadIdx.x;
  const int lane = tid & 63;
  const int wave = tid >> 6;
  const int wr = (wave >> 1) * 64;
  const int wc = (wave & 1) * 64;
  const int fr = lane & 15;
  const int kq = (lane >> 4) * 8;  // element offset within 32-k step

  f32x4 acc[4][4] = {};

  for (int k0 = 0; k0 < K; k0 += 64) {
    __syncthreads();
    const unsigned short* Asrc;
    int ka;
    if (LAYER == 2 && k0 >= DIMS) {
      Asrc = A2;
      ka = k0 - DIMS;
    } else {
      Asrc = A1;
      ka = k0;
    }
#pragma unroll
    for (int i = 0; i < 4; i++) {
      const int g = i * 256 + tid;
      const int r = g >> 3;
      const int c = (g & 7) * 8;
      GLL16(Asrc + (size_t)(row0 + r) * DIMS + ka + c, &As[g * 8]);
    }
#pragma unroll
    for (int i = 0; i < 4; i++) {
      const int g = i * 256 + tid;
      const int r = g >> 3;
      const int c = (g & 7) * 8;
      GLL16(Wt + (size_t)(n0 + r) * K + k0 + c, &Bs[g * 8]);
    }
    __syncthreads();

#pragma unroll
    for (int h = 0; h < 2; h++) {
      s16x8 av[4], bv[4];
#pragma unroll
      for (int m = 0; m < 4; m++)
        av[m] = *(const s16x8*)&As[(wr + m * 16 + fr) * 64 + h * 32 + kq];
#pragma unroll
      for (int n = 0; n < 4; n++)
        bv[n] = *(const s16x8*)&Bs[(wc + n * 16 + fr) * 64 + h * 32 + kq];
#pragma unroll
      for (int m = 0; m < 4; m++)
#pragma unroll
        for (int n = 0; n < 4; n++)
          acc[m][n] = __builtin_amdgcn_mfma_f32_16x16x32_bf16(av[m], bv[n], acc[m][n], 0, 0, 0);
    }
  }

  // epilogue: D mapping col=lane&15, row=(lane>>4)*4+j
  const int rq = (lane >> 4) * 4;
#pragma unroll
  for (int m = 0; m < 4; m++) {
#pragma unroll
    for (int n = 0; n < 4; n++) {
      const int col = n0 + wc + n * 16 + fr;
#pragma unroll
      for (int j = 0; j < 4; j++) {
        const int row = row0 + wr + m * 16 + rq + j;
        if (row < M) Hout[(size_t)row * DIMS + col] = f2bf(acc[m][n][j]);
      }
    }
  }
}

// ---------------- aggregation: acc = bias + dinv^2*H[i] + sum_in w*H[src], H bf16 ------
// MODE 1: out = bf16 leaky (layer-1 y). MODE 2: out = f32 z, + fused pooler a.
// Edge loop software-pipelined 2-wide: 6 independent gather loads in flight.

template <int MODE>
__global__ void agg_kernel(const unsigned short* __restrict__ H, const float* __restrict__ bias,
                           const float* __restrict__ dinv, const int* __restrict__ off,
                           const int* __restrict__ cnt, const int* __restrict__ csr_s,
                           const float* __restrict__ csr_w, void* __restrict__ outp,
                           const float* __restrict__ Wp, const float* __restrict__ bp,
                           float* __restrict__ A, int n) {
  const int wid = (blockIdx.x * blockDim.x + threadIdx.x) >> 6;
  const int lane = threadIdx.x & 63;
  if (wid >= n) return;
  const float ds = dinv[wid];
  const float ws = ds * ds;
  const unsigned short* hr = H + (size_t)wid * DIMS;
  float acc[6];
#pragma unroll
  for (int j = 0; j < 3; j++) {
    const int d = 2 * lane + 128 * j;
    unsigned v = *(const unsigned*)(hr + d);
    acc[2 * j] = bias[d] + ws * bf2f((unsigned short)v);
    acc[2 * j + 1] = bias[d + 1] + ws * bf2f((unsigned short)(v >> 16));
  }
  const int e0 = off[wid];
  const int e1 = e0 + cnt[wid];
  int e = e0;
  for (; e + 2 <= e1; e += 2) {
    const int sA = csr_s[e], sB = csr_s[e + 1];
    const float wA = csr_w[e], wB = csr_w[e + 1];
    const unsigned short* hA = H + (size_t)sA * DIMS;
    const unsigned short* hB = H + (size_t)sB * DIMS;
    unsigned vA[3], vB[3];
#pragma unroll
    for (int j = 0; j < 3; j++) vA[j] = *(const unsigned*)(hA + 2 * lane + 128 * j);
#pragma unroll
    for (int j = 0; j < 3; j++) vB[j] = *(const unsigned*)(hB + 2 * lane + 128 * j);
#pragma unroll
    for (int j = 0; j < 3; j++) {
      acc[2 * j] += wA * bf2f((unsigned short)vA[j]);
      acc[2 * j + 1] += wA * bf2f((unsigned short)(vA[j] >> 16));
      acc[2 * j] += wB * bf2f((unsigned short)vB[j]);
      acc[2 * j + 1] += wB * bf2f((unsigned short)(vB[j] >> 16));
    }
  }
  if (e < e1) {
    const int s = csr_s[e];
    const float w = csr_w[e];
    const unsigned short* hs = H + (size_t)s * DIMS;
#pragma unroll
    for (int j = 0; j < 3; j++) {
      unsigned v = *(const unsigned*)(hs + 2 * lane + 128 * j);
      acc[2 * j] += w * bf2f((unsigned short)v);
      acc[2 * j + 1] += w * bf2f((unsigned short)(v >> 16));
    }
  }
  if (MODE == 1) {
    unsigned short* o = (unsigned short*)outp + (size_t)wid * DIMS;
#pragma unroll
    for (int j = 0; j < 3; j++) {
      unsigned lo = f2bf(leaky(acc[2 * j]));
      unsigned hi = f2bf(leaky(acc[2 * j + 1]));
      *(unsigned*)(o + 2 * lane + 128 * j) = lo | (hi << 16);
    }
  } else {
    float* Z = (float*)outp + (size_t)wid * DIMS;
    float dot = 0.f;
#pragma unroll
    for (int j = 0; j < 3; j++) {
      float z0 = leaky(acc[2 * j]);
      float z1 = leaky(acc[2 * j + 1]);
      f32x2 wp = *(const f32x2*)(Wp + 2 * lane + 128 * j);
      f32x2 zv = {z0, z1};
      // z is never re-read: nontemporal keeps H resident in LLC
      __builtin_nontemporal_store(zv, (f32x2*)(Z + 2 * lane + 128 * j));
      dot += z0 * wp.x + z1 * wp.y;
    }
#pragma unroll
    for (int o = 32; o > 0; o >>= 1) dot += __shfl_xor(dot, o);
    if (lane == 0) A[wid] = dot + bp[0];
  }
}

// ---------------- launch ----------------

extern "C" void kernel_launch(void* const* d_in, const int* in_sizes, int n_in,
                              void* d_out, int out_size, void* d_ws, size_t ws_size,
                              hipStream_t stream) {
  const float* x = (const float*)d_in[0];
  const int* ei = (const int*)d_in[1];
  const float* W1 = (const float*)d_in[2];
  const float* b1 = (const float*)d_in[3];
  const float* W2 = (const float*)d_in[4];
  const float* b2 = (const float*)d_in[5];
  const float* Wp = (const float*)d_in[6];
  const float* bp = (const float*)d_in[7];
  const int N = in_sizes[0] / DIMS;  // 100000
  const int E = in_sizes[1] / 2;     // 400000
  const int* src = ei;
  const int* dst = ei + E;
  const int NP = N + 128;  // row-padded

  char* p = (char*)d_ws;
  auto alloc = [&](size_t bytes) {
    char* r = p;
    p += (bytes + 255) & ~(size_t)255;
    return r;
  };
  // RegionA: [ Xb bf16 (NP rows) | H1 bf16 (NP rows) ]; H2 (bf16, NP rows) reuses the
  // Xb slot. Hazards: Xb dead after gemm1; H1 dead after agg1; gemm2 writes H2 after both.
  char* regionA = alloc(2 * (size_t)NP * DIMS * 2);
  unsigned short* Xb = (unsigned short*)regionA;
  unsigned short* H1 = (unsigned short*)(regionA + (size_t)NP * DIMS * 2);
  unsigned short* H2 = (unsigned short*)regionA;
  unsigned short* XbL = (unsigned short*)alloc((size_t)NP * DIMS * 2);
  unsigned short* YBL = (unsigned short*)alloc((size_t)NP * DIMS * 2);
  float* dinv = (float*)alloc((size_t)N * 4);
  int* cnt = (int*)alloc((size_t)(N + 1) * 4);
  int* tot = cnt + N;
  int* off = (int*)alloc((size_t)N * 4);
  int* cursor = (int*)alloc((size_t)N * 4);
  int* csr_s = (int*)alloc((size_t)E * 4);
  float* csr_w = (float*)alloc((size_t)E * 4);
  unsigned short* Wt1 = (unsigned short*)alloc((size_t)DIMS * DIMS * 2);
  unsigned short* Wt2 = (unsigned short*)alloc((size_t)DIMS * 2 * DIMS * 2);

  float* z = (float*)d_out;
  float* a = z + (size_t)N * DIMS;

  const int nbN = (N + 255) / 256;
  const int nbE = (E + 255) / 256;

  hipMemsetAsync(cnt, 0, (size_t)(N + 1) * 4, stream);
  count_kernel<<<nbE, 256, 0, stream>>>(dst, cnt, E);
  node_prep_kernel<<<nbN, 256, 0, stream>>>(cnt, tot, dinv, off, cursor, N);
  fill_kernel<<<nbE, 256, 0, stream>>>(src, dst, dinv, cursor, csr_s, csr_w, E);
  wt_kernel<<<(DIMS * DIMS + 255) / 256, 256, 0, stream>>>(W1, Wt1, DIMS);
  wt_kernel<<<(2 * DIMS * DIMS + 255) / 256, 256, 0, stream>>>(W2, Wt2, 2 * DIMS);
  const int total8 = N * DIMS / 8;
  xprep_kernel<<<(total8 + 255) / 256, 256, 0, stream>>>(x, Xb, XbL, total8);

  const int nwg = ((N + 127) / 128) * 3;  // row-panel-major x 3 col-blocks
  gemm_kernel<1><<<nwg, 256, 0, stream>>>(Xb, nullptr, Wt1, H1, N, DIMS);
  agg_kernel<1><<<(N + 3) / 4, 256, 0, stream>>>(H1, b1, dinv, off, cnt, csr_s, csr_w, YBL,
                                                 nullptr, nullptr, nullptr, N);
  gemm_kernel<2><<<nwg, 256, 0, stream>>>(XbL, YBL, Wt2, H2, N, 2 * DIMS);
  agg_kernel<2><<<(N + 3) / 4, 256, 0, stream>>>(H2, b2, dinv, off, cnt, csr_s, csr_w, z,
                                                 Wp, bp, a, N);
}